// Round 1
// baseline (284.022 us; speedup 1.0000x reference)
//
#include <hip/hip_runtime.h>

// Problem constants
#define N 8
#define C 64
#define H 256
#define W 256
#define G 8
#define CG 8            // C/G
#define KK 9            // 3x3
#define HW (H*W)        // 65536

// ---------------------------------------------------------------------------
// Kernel 1: global average pool per (n,c).  One block per (n,c), 256 threads,
// float4 loads, wave-shuffle reduce.
// ---------------------------------------------------------------------------
__global__ __launch_bounds__(256) void gap_kernel(const float* __restrict__ x,
                                                  float* __restrict__ gap) {
    const int nc = blockIdx.x;                     // 0..511
    const float4* x4 = (const float4*)(x + (size_t)nc * HW);
    float s = 0.f;
    // 65536 floats = 16384 float4; 256 threads -> 64 iters each
    for (int i = threadIdx.x; i < HW / 4; i += 256) {
        float4 v = x4[i];
        s += (v.x + v.y) + (v.z + v.w);
    }
    // wave (64-lane) shuffle reduce
    #pragma unroll
    for (int off = 32; off > 0; off >>= 1)
        s += __shfl_down(s, off, 64);
    __shared__ float red[4];
    const int wave = threadIdx.x >> 6;
    const int lane = threadIdx.x & 63;
    if (lane == 0) red[wave] = s;
    __syncthreads();
    if (threadIdx.x == 0) {
        float t = (red[0] + red[1]) + (red[2] + red[3]);
        gap[nc] = t * (1.0f / (float)HW);
    }
}

// ---------------------------------------------------------------------------
// Kernel 2: filt[n, o] = tanh( dot(gap[n,:], conv_w[o,:]) ), o in [0,72)
// 576 outputs total -- trivial.
// ---------------------------------------------------------------------------
__global__ __launch_bounds__(256) void filt_kernel(const float* __restrict__ gap,
                                                   const float* __restrict__ conv_w,
                                                   float* __restrict__ filt) {
    const int idx = blockIdx.x * 256 + threadIdx.x;
    if (idx >= N * G * KK) return;
    const int n = idx / (G * KK);
    const int o = idx - n * (G * KK);
    const float* gp = gap + n * C;
    const float* wp = conv_w + o * C;
    float s = 0.f;
    #pragma unroll
    for (int c = 0; c < C; ++c) s += gp[c] * wp[c];
    filt[idx] = tanhf(s);
}

// ---------------------------------------------------------------------------
// Kernel 3: out[n,c,h,w] = x[n,c,h,w] + sum_{i,j} xp[n,c,h+i-1,w+j-1]*f[n,g,ij]
// reflect padding (exclude-edge): index -1 -> 1, index 256 -> 254.
// Block = 256 threads = 4 rows x 64 threads; each thread emits one float4.
// Grid = N*C*(H/4) = 32768 blocks.
// ---------------------------------------------------------------------------
__global__ __launch_bounds__(256) void dynconv_kernel(const float* __restrict__ x,
                                                      const float* __restrict__ filt,
                                                      float* __restrict__ out) {
    const int bid = blockIdx.x;
    const int rowblk = bid & (H / 4 - 1);          // 0..63
    const int nc = bid >> 6;                       // n*C + c
    const int n = nc >> 6;
    const int c = nc & (C - 1);
    const int g = c >> 3;                          // c / CG

    const float* f = filt + ((size_t)n * G + g) * KK;
    const float f00 = f[0], f01 = f[1], f02 = f[2];
    const float f10 = f[3], f11 = f[4], f12 = f[5];
    const float f20 = f[6], f21 = f[7], f22 = f[8];

    const int tid = threadIdx.x;
    const int lrow = tid >> 6;                     // 0..3
    const int wq = (tid & 63) * 4;                 // base column of the float4
    const int hrow = rowblk * 4 + lrow;

    const float* xc = x + (size_t)nc * HW;
    // reflect rows
    int hm = hrow - 1; if (hm < 0) hm = 1;
    int hp = hrow + 1; if (hp >= H) hp = H - 2;

    const float* rm = xc + (size_t)hm * W;
    const float* rc = xc + (size_t)hrow * W;
    const float* rp = xc + (size_t)hp * W;

    // Load 6-wide strips [wq-1 .. wq+4] for each of the 3 rows (reflect cols)
    float vm[6], vc[6], vp[6];
    {
        float4 a = *(const float4*)(rm + wq);
        vm[1] = a.x; vm[2] = a.y; vm[3] = a.z; vm[4] = a.w;
        vm[0] = (wq == 0) ? rm[1] : rm[wq - 1];
        vm[5] = (wq == W - 4) ? rm[W - 2] : rm[wq + 4];
    }
    {
        float4 a = *(const float4*)(rc + wq);
        vc[1] = a.x; vc[2] = a.y; vc[3] = a.z; vc[4] = a.w;
        vc[0] = (wq == 0) ? rc[1] : rc[wq - 1];
        vc[5] = (wq == W - 4) ? rc[W - 2] : rc[wq + 4];
    }
    {
        float4 a = *(const float4*)(rp + wq);
        vp[1] = a.x; vp[2] = a.y; vp[3] = a.z; vp[4] = a.w;
        vp[0] = (wq == 0) ? rp[1] : rp[wq - 1];
        vp[5] = (wq == W - 4) ? rp[W - 2] : rp[wq + 4];
    }

    float o4[4];
    #pragma unroll
    for (int k = 0; k < 4; ++k) {
        float acc = vc[k + 1];                     // residual x
        acc += f00 * vm[k] + f01 * vm[k + 1] + f02 * vm[k + 2];
        acc += f10 * vc[k] + f11 * vc[k + 1] + f12 * vc[k + 2];
        acc += f20 * vp[k] + f21 * vp[k + 1] + f22 * vp[k + 2];
        o4[k] = acc;
    }

    float4 r;
    r.x = o4[0]; r.y = o4[1]; r.z = o4[2]; r.w = o4[3];
    *(float4*)(out + (size_t)nc * HW + (size_t)hrow * W + wq) = r;
}

// ---------------------------------------------------------------------------
extern "C" void kernel_launch(void* const* d_in, const int* in_sizes, int n_in,
                              void* d_out, int out_size, void* d_ws, size_t ws_size,
                              hipStream_t stream) {
    const float* x      = (const float*)d_in[0];
    const float* conv_w = (const float*)d_in[1];
    float* out = (float*)d_out;

    float* gap  = (float*)d_ws;                    // 512 floats
    float* filt = (float*)d_ws + 512;              // 576 floats

    gap_kernel<<<N * C, 256, 0, stream>>>(x, gap);
    filt_kernel<<<(N * G * KK + 255) / 256, 256, 0, stream>>>(gap, conv_w, filt);
    dynconv_kernel<<<N * C * (H / 4), 256, 0, stream>>>(x, filt, out);
}